// Round 12
// baseline (137.089 us; speedup 1.0000x reference)
//
#include <hip/hip_runtime.h>
#include <stdint.h>

// ============================ problem dims ============================
// hidden_states [4,2048,2048] f32, rows R=8192, H=2048, BD=N=VBD=256, top-8
// out = primary + sigmoid(top1) * gelu_lowrank(softmax_top8 @ gathered vals)
// Key restructure: down-proj is linear -> precompute PV = slot_values @ Wd^T
// (256x256) and gather from PV instead of materializing aux[8192][2048].
// R11 restructure: k_query+k_score FUSED (no qp split-K round-trip: -48 MB).

typedef float f32x4 __attribute__((ext_vector_type(4)));
typedef unsigned short u16x8 __attribute__((ext_vector_type(8)));
typedef unsigned short u16x4 __attribute__((ext_vector_type(4)));
typedef __bf16 bf16x8 __attribute__((ext_vector_type(8)));

// ============================ ws layout (bytes) ============================
#define WS_QW    0u          // u16 [256*2048]  q_proj_w bf16
#define WS_SK    1048576u    // u16 [256*256]   slot_keys bf16
#define WS_SV    1179648u    // u16 [256*2048]  slot_values bf16
#define WS_VDW   2228224u    // u16 [256*2048]  value_down_w bf16
#define WS_VUP   3276800u    // u16 [2048*256]  value_up_w bf16
#define WS_REL   4325376u    // f32 [256]       log(reliability)
#define WS_PV    4326400u    // f32 [256*256]   slot_values @ Wd^T
#define WS_GATE  4588544u    // f32 [8192]      sigmoid(top1)
#define WS_D     21398528u   // u16 [8192*256]  gelu(down) bf16

static __device__ __forceinline__ unsigned short f2bf(float f) {
  union { float f; unsigned int u; } v; v.f = f;
  unsigned int r = v.u + 0x7FFFu + ((v.u >> 16) & 1u);
  return (unsigned short)(r >> 16);
}
static __device__ __forceinline__ bf16x8 as_bf16(u16x8 v) {
  return __builtin_bit_cast(bf16x8, v);
}
static __device__ __forceinline__ float gelu_tanh(float x) {
  float u = 0.7978845608028654f * (x + 0.044715f * x * x * x);
  return 0.5f * x * (1.0f + tanhf(u));
}

// ============================ K0: convert weights ============================
__global__ void k_prep(const float* __restrict__ qw, const float* __restrict__ sk,
                       const float* __restrict__ sv, const float* __restrict__ vdw,
                       const float* __restrict__ vup, const float* __restrict__ rel,
                       unsigned char* __restrict__ ws) {
  unsigned short* o_qw  = (unsigned short*)(ws + WS_QW);
  unsigned short* o_sk  = (unsigned short*)(ws + WS_SK);
  unsigned short* o_sv  = (unsigned short*)(ws + WS_SV);
  unsigned short* o_vdw = (unsigned short*)(ws + WS_VDW);
  unsigned short* o_vup = (unsigned short*)(ws + WS_VUP);
  float* o_rel = (float*)(ws + WS_REL);
  int tid = blockIdx.x * blockDim.x + threadIdx.x;
  int stride = gridDim.x * blockDim.x;
  for (int g = tid; g < 540736; g += stride) {
    const float* src; unsigned short* dst; int i;
    if      (g < 131072) { src = qw;  dst = o_qw;  i = g; }
    else if (g < 147456) { src = sk;  dst = o_sk;  i = g - 131072; }
    else if (g < 278528) { src = sv;  dst = o_sv;  i = g - 147456; }
    else if (g < 409600) { src = vdw; dst = o_vdw; i = g - 278528; }
    else if (g < 540672) { src = vup; dst = o_vup; i = g - 409600; }
    else {
      int i4 = (g - 540672) * 4;
      #pragma unroll
      for (int j = 0; j < 4; j++) o_rel[i4 + j] = logf(fmaxf(rel[i4 + j], 1e-10f));
      continue;
    }
    f32x4 v = *(const f32x4*)(src + (size_t)i * 4);
    u16x4 o;
    #pragma unroll
    for (int j = 0; j < 4; j++) o[j] = f2bf(v[j]);
    *(u16x4*)(dst + (size_t)i * 4) = o;
  }
}

// ============================ K_PV: PV = sv @ vdw^T ============================
__global__ __launch_bounds__(256, 2) void k_pv(unsigned char* __restrict__ ws) {
  const unsigned short* sv  = (const unsigned short*)(ws + WS_SV);
  const unsigned short* vdw = (const unsigned short*)(ws + WS_VDW);
  float* PV = (float*)(ws + WS_PV);
  __shared__ __align__(16) unsigned short As[32 * 64];
  __shared__ __align__(16) unsigned short Bs[32 * 64];
  int t = threadIdx.x, lane = t & 63, w = t >> 6;
  int nt = blockIdx.x >> 3, vt = blockIdx.x & 7;
  int mf = w >> 1, nf = w & 1;
  f32x4 acc = {0.f, 0.f, 0.f, 0.f};
  int r = t >> 3, c = t & 7;
  int sw8 = (c ^ (r & 7)) * 8;
  for (int k0 = 0; k0 < 2048; k0 += 64) {
    __syncthreads();
    *(u16x8*)&As[r * 64 + sw8] = *(const u16x8*)&sv[(size_t)(nt * 32 + r) * 2048 + k0 + c * 8];
    *(u16x8*)&Bs[r * 64 + sw8] = *(const u16x8*)&vdw[(size_t)(vt * 32 + r) * 2048 + k0 + c * 8];
    __syncthreads();
    #pragma unroll
    for (int kk = 0; kk < 2; kk++) {
      int ck = kk * 4 + (lane >> 4);
      int ar = mf * 16 + (lane & 15);
      int br = nf * 16 + (lane & 15);
      bf16x8 a = as_bf16(*(const u16x8*)&As[ar * 64 + ((ck ^ (ar & 7)) * 8)]);
      bf16x8 b = as_bf16(*(const u16x8*)&Bs[br * 64 + ((ck ^ (br & 7)) * 8)]);
      acc = __builtin_amdgcn_mfma_f32_16x16x32_bf16(a, b, acc, 0, 0, 0);
    }
  }
  int row = nt * 32 + mf * 16 + (lane >> 4) * 4;
  int col = vt * 32 + nf * 16 + (lane & 15);
  #pragma unroll
  for (int j = 0; j < 4; j++) PV[(row + j) * 256 + col] = acc[j];
}

// ============================ K1: FUSED query GEMM + scores + top8 + PV ============================
// 512 blocks x 16 rows.  GEMM-1: query[16][256] = hs[rows,:] @ qw^T over full
// K=2048 (reg-prefetch pipelined, acc in regs -> NO qp round-trip).  Then
// query -> bf16 -> LDS; GEMM-2: scores = Q @ sk^T /16 + rel; wave-parallel
// top8 (pack score|idx u32, 8x butterfly max); softmax+gate; coalesced PV
// gather; gelu -> D bf16.  LDS: As 2KB + union(B staging 32KB | Qs+Ss 25KB).
#define QSTR 264   // ushort stride
#define SSTR 260   // f32 stride
union QScoreLds {
  unsigned short B[256 * 64];            // GEMM-1 qw staging (32 KB)
  struct {
    unsigned short Qs[16 * QSTR];        // 8448 B
    float Ss[16 * SSTR];                 // 16640 B
  } s;
};
__global__ __launch_bounds__(256, 4) void k_qscore(const float* __restrict__ hs,
                                                   unsigned char* __restrict__ ws) {
  const unsigned short* qw = (const unsigned short*)(ws + WS_QW);
  const unsigned short* sk = (const unsigned short*)(ws + WS_SK);
  const float* relm = (const float*)(ws + WS_REL);
  const float* PV = (const float*)(ws + WS_PV);
  float* gates = (float*)(ws + WS_GATE);
  unsigned short* D = (unsigned short*)(ws + WS_D);
  __shared__ __align__(16) unsigned short As[16 * 64];   // 2 KB
  __shared__ __align__(16) QScoreLds u;
  int t = threadIdx.x, lane = t & 63, w = t >> 6;
  int row0 = blockIdx.x * 16;
  // ---- GEMM-1: K-pipelined over K=2048, BK=64 ----
  int sr = t >> 3, sc = t & 7;                   // B staging: rows i*32+sr
  int asr = (t & 127) >> 3;                      // A staging rows [0,16) (t<128)
  const float* aptr = hs + (size_t)(row0 + asr) * 2048 + sc * 8;
  const unsigned short* bptr = qw + (size_t)sr * 2048 + sc * 8;
  f32x4 pa0, pa1;
  u16x8 pb0, pb1, pb2, pb3, pb4, pb5, pb6, pb7;
  if (t < 128) { pa0 = *(const f32x4*)(aptr); pa1 = *(const f32x4*)(aptr + 4); }
  pb0 = *(const u16x8*)(bptr + (size_t)0 * 32 * 2048);
  pb1 = *(const u16x8*)(bptr + (size_t)1 * 32 * 2048);
  pb2 = *(const u16x8*)(bptr + (size_t)2 * 32 * 2048);
  pb3 = *(const u16x8*)(bptr + (size_t)3 * 32 * 2048);
  pb4 = *(const u16x8*)(bptr + (size_t)4 * 32 * 2048);
  pb5 = *(const u16x8*)(bptr + (size_t)5 * 32 * 2048);
  pb6 = *(const u16x8*)(bptr + (size_t)6 * 32 * 2048);
  pb7 = *(const u16x8*)(bptr + (size_t)7 * 32 * 2048);
  f32x4 accq[4] = {};
  for (int kt = 0; kt < 32; kt++) {
    __syncthreads();   // previous tile's LDS readers done
    if (t < 128) {     // A: 16x64 fp32 -> bf16, swizzled
      u16x8 o;
      #pragma unroll
      for (int j = 0; j < 4; j++) { o[j] = f2bf(pa0[j]); o[4 + j] = f2bf(pa1[j]); }
      *(u16x8*)&As[asr * 64 + ((sc ^ (asr & 7)) * 8)] = o;
    }
    {  // B: 256x64, swizzled
      u16x8 pb[8] = {pb0, pb1, pb2, pb3, pb4, pb5, pb6, pb7};
      #pragma unroll
      for (int i = 0; i < 8; i++) {
        int n = i * 32 + sr;
        *(u16x8*)&u.B[n * 64 + ((sc ^ (n & 7)) * 8)] = pb[i];
      }
    }
    __syncthreads();
    if (kt < 31) {  // prefetch tile kt+1 (overlaps MFMA below)
      int off = (kt + 1) * 64;
      if (t < 128) { pa0 = *(const f32x4*)(aptr + off); pa1 = *(const f32x4*)(aptr + off + 4); }
      pb0 = *(const u16x8*)(bptr + (size_t)0 * 32 * 2048 + off);
      pb1 = *(const u16x8*)(bptr + (size_t)1 * 32 * 2048 + off);
      pb2 = *(const u16x8*)(bptr + (size_t)2 * 32 * 2048 + off);
      pb3 = *(const u16x8*)(bptr + (size_t)3 * 32 * 2048 + off);
      pb4 = *(const u16x8*)(bptr + (size_t)4 * 32 * 2048 + off);
      pb5 = *(const u16x8*)(bptr + (size_t)5 * 32 * 2048 + off);
      pb6 = *(const u16x8*)(bptr + (size_t)6 * 32 * 2048 + off);
      pb7 = *(const u16x8*)(bptr + (size_t)7 * 32 * 2048 + off);
    }
    #pragma unroll
    for (int kk = 0; kk < 2; kk++) {
      int ck = kk * 4 + (lane >> 4);
      int arow = lane & 15;
      bf16x8 a = as_bf16(*(const u16x8*)&As[arow * 64 + ((ck ^ (arow & 7)) * 8)]);
      #pragma unroll
      for (int nf = 0; nf < 4; nf++) {
        int brow = w * 64 + nf * 16 + (lane & 15);
        bf16x8 b = as_bf16(*(const u16x8*)&u.B[brow * 64 + ((ck ^ (brow & 7)) * 8)]);
        accq[nf] = __builtin_amdgcn_mfma_f32_16x16x32_bf16(a, b, accq[nf], 0, 0, 0);
      }
    }
  }
  __syncthreads();   // all B reads done; union region becomes Qs/Ss
  // ---- query -> bf16 -> Qs ----
  #pragma unroll
  for (int nf = 0; nf < 4; nf++) {
    int col = w * 64 + nf * 16 + (lane & 15);
    int rr = (lane >> 4) * 4;
    #pragma unroll
    for (int j = 0; j < 4; j++)
      u.s.Qs[(rr + j) * QSTR + col] = f2bf(accq[nf][j]);
  }
  __syncthreads();
  // ---- GEMM-2: scores[16][256] = Q @ sk^T / 16 + rel_mask ----
  {
    f32x4 acc[4] = {};
    for (int ksb = 0; ksb < 8; ksb++) {
      int ck = lane >> 4;
      bf16x8 a = as_bf16(*(const u16x8*)&u.s.Qs[(lane & 15) * QSTR + ksb * 32 + ck * 8]);
      #pragma unroll
      for (int nf = 0; nf < 4; nf++) {
        int n = w * 64 + nf * 16 + (lane & 15);
        bf16x8 b = as_bf16(*(const u16x8*)&sk[(size_t)n * 256 + ksb * 32 + ck * 8]);
        acc[nf] = __builtin_amdgcn_mfma_f32_16x16x32_bf16(a, b, acc[nf], 0, 0, 0);
      }
    }
    #pragma unroll
    for (int nf = 0; nf < 4; nf++) {
      int n = w * 64 + nf * 16 + (lane & 15);
      float rm = relm[n];
      int rr = (lane >> 4) * 4;
      #pragma unroll
      for (int j = 0; j < 4; j++) u.s.Ss[(rr + j) * SSTR + n] = acc[nf][j] * 0.0625f + rm;
    }
  }
  __syncthreads();
  // ---- phase 3: wave w handles rows w*4 .. w*4+3 ----
  for (int rr = 0; rr < 4; rr++) {
    int row = w * 4 + rr;
    f32x4 sv4 = *(const f32x4*)&u.s.Ss[row * SSTR + lane * 4];
    unsigned int key[4];
    #pragma unroll
    for (int j = 0; j < 4; j++) {
      unsigned int uu = __builtin_bit_cast(unsigned int, sv4[j]);
      unsigned int os = (uu & 0x80000000u) ? ~uu : (uu | 0x80000000u);
      key[j] = (os & 0xFFFFFF00u) | (unsigned int)(255 - (lane * 4 + j));
    }
    unsigned int win[8];
    #pragma unroll
    for (int e = 0; e < 8; e++) {
      unsigned int m01 = key[0] > key[1] ? key[0] : key[1];
      unsigned int m23 = key[2] > key[3] ? key[2] : key[3];
      unsigned int m = m01 > m23 ? m01 : m23;
      #pragma unroll
      for (int d = 1; d < 64; d <<= 1) {
        unsigned int o = (unsigned int)__shfl_xor((int)m, d, 64);
        m = o > m ? o : m;
      }
      win[e] = m;
      #pragma unroll
      for (int j = 0; j < 4; j++) if (key[j] == m) key[j] = 0u;
    }
    float s8[8]; int i8[8];
    #pragma unroll
    for (int e = 0; e < 8; e++) {
      i8[e] = 255 - (int)(win[e] & 0xFFu);
      unsigned int os = win[e] & 0xFFFFFF00u;
      unsigned int uu = (os & 0x80000000u) ? (os ^ 0x80000000u) : ~os;
      s8[e] = __builtin_bit_cast(float, uu);
    }
    float m0 = s8[0], sum = 0.f, we[8];
    #pragma unroll
    for (int e = 0; e < 8; e++) { we[e] = expf(s8[e] - m0); sum += we[e]; }
    float inv = 1.f / sum;
    f32x4 accv = {0.f, 0.f, 0.f, 0.f};
    #pragma unroll
    for (int e = 0; e < 8; e++) {
      float wk = we[e] * inv;
      f32x4 p = *(const f32x4*)(PV + (size_t)i8[e] * 256 + lane * 4);
      #pragma unroll
      for (int j = 0; j < 4; j++) accv[j] += wk * p[j];
    }
    u16x4 o;
    #pragma unroll
    for (int j = 0; j < 4; j++) o[j] = f2bf(gelu_tanh(accv[j]));
    *(u16x4*)&D[(size_t)(row0 + row) * 256 + lane * 4] = o;
    if (lane == 0) gates[row0 + row] = 1.f / (1.f + expf(-m0));
  }
}

// ============================ K3: up-GEMM + epilogue (R9 best variant, 6 blk/CU) ============================
union KOutLds {
  unsigned short AB[12288];        // As = AB[0..4095] (64x64), Bs = AB+4096 (128x64)
  float stage[32 * 132];           // epilogue restage
};
__global__ __launch_bounds__(256, 6) void k_out(const float* __restrict__ primary,
                                                float* __restrict__ out,
                                                unsigned char* __restrict__ ws) {
  const unsigned short* D = (const unsigned short*)(ws + WS_D);
  const unsigned short* vup = (const unsigned short*)(ws + WS_VUP);
  const float* gates = (const float*)(ws + WS_GATE);
  __shared__ __align__(16) KOutLds u;
  __shared__ float gate_s[64];
  unsigned short* As = u.AB;
  unsigned short* Bs = u.AB + 4096;
  int t = threadIdx.x, lane = t & 63, w = t >> 6;
  int bid = blockIdx.x;
  int L = (bid & 7) * 256 + (bid >> 3);   // bijective: 2048 % 8 == 0
  int rt = L >> 4, ct = L & 15;
  int wm = w >> 1, wn = w & 1;
  const float* pbase = primary + (size_t)(rt * 64 + (t >> 5)) * 2048 + ct * 128 + (t & 31) * 4;
  f32x4 pref[2][4];
  #pragma unroll
  for (int i = 0; i < 4; i++)
    pref[0][i] = *(const f32x4*)(pbase + (size_t)(i * 8) * 2048);
  int sr = t >> 3, sc = t & 7;
  const unsigned short* aptr = D + (size_t)(rt * 64 + sr) * 256 + sc * 8;
  const unsigned short* bptr = vup + (size_t)(ct * 128 + sr) * 256 + sc * 8;
  u16x8 pA0, pA1, pB0, pB1, pB2, pB3;
  pA0 = *(const u16x8*)(aptr);
  pA1 = *(const u16x8*)(aptr + 32 * 256);
  pB0 = *(const u16x8*)(bptr);
  pB1 = *(const u16x8*)(bptr + 32 * 256);
  pB2 = *(const u16x8*)(bptr + 64 * 256);
  pB3 = *(const u16x8*)(bptr + 96 * 256);
  if (t < 64) gate_s[t] = gates[rt * 64 + t];
  f32x4 acc[2][4] = {};
  for (int k0 = 0; k0 < 256; k0 += 64) {
    __syncthreads();
    {
      int r0 = sr, r1 = sr + 32, r2 = sr + 64, r3 = sr + 96;
      *(u16x8*)&As[r0 * 64 + ((sc ^ (r0 & 7)) * 8)] = pA0;
      *(u16x8*)&As[r1 * 64 + ((sc ^ (r1 & 7)) * 8)] = pA1;
      *(u16x8*)&Bs[r0 * 64 + ((sc ^ (r0 & 7)) * 8)] = pB0;
      *(u16x8*)&Bs[r1 * 64 + ((sc ^ (r1 & 7)) * 8)] = pB1;
      *(u16x8*)&Bs[r2 * 64 + ((sc ^ (r2 & 7)) * 8)] = pB2;
      *(u16x8*)&Bs[r3 * 64 + ((sc ^ (r3 & 7)) * 8)] = pB3;
    }
    __syncthreads();
    if (k0 < 192) {
      int off = k0 + 64;
      pA0 = *(const u16x8*)(aptr + off);
      pA1 = *(const u16x8*)(aptr + 32 * 256 + off);
      pB0 = *(const u16x8*)(bptr + off);
      pB1 = *(const u16x8*)(bptr + 32 * 256 + off);
      pB2 = *(const u16x8*)(bptr + 64 * 256 + off);
      pB3 = *(const u16x8*)(bptr + 96 * 256 + off);
    }
    #pragma unroll
    for (int kk = 0; kk < 2; kk++) {
      int ck = kk * 4 + (lane >> 4);
      bf16x8 a[2], b[4];
      #pragma unroll
      for (int mf = 0; mf < 2; mf++) {
        int ar = wm * 32 + mf * 16 + (lane & 15);
        a[mf] = as_bf16(*(const u16x8*)&As[ar * 64 + ((ck ^ (ar & 7)) * 8)]);
      }
      #pragma unroll
      for (int nf = 0; nf < 4; nf++) {
        int br = wn * 64 + nf * 16 + (lane & 15);
        b[nf] = as_bf16(*(const u16x8*)&Bs[br * 64 + ((ck ^ (br & 7)) * 8)]);
      }
      #pragma unroll
      for (int mf = 0; mf < 2; mf++)
        #pragma unroll
        for (int nf = 0; nf < 4; nf++)
          acc[mf][nf] = __builtin_amdgcn_mfma_f32_16x16x32_bf16(a[mf], b[nf], acc[mf][nf], 0, 0, 0);
    }
  }
  #pragma unroll
  for (int c = 0; c < 2; c++) {
    __syncthreads();
    if (wm == c) {
      #pragma unroll
      for (int mf = 0; mf < 2; mf++) {
        #pragma unroll
        for (int nf = 0; nf < 4; nf++) {
          int col = wn * 64 + nf * 16 + (lane & 15);
          #pragma unroll
          for (int j = 0; j < 4; j++) {
            int r = mf * 16 + (lane >> 4) * 4 + j;
            u.stage[r * 132 + col] = acc[mf][nf][j];
          }
        }
      }
    }
    if (c == 0) {
      #pragma unroll
      for (int i = 0; i < 4; i++)
        pref[1][i] = *(const f32x4*)(pbase + (size_t)(32 + i * 8) * 2048);
    }
    __syncthreads();
    #pragma unroll
    for (int i = 0; i < 4; i++) {
      int idx = i * 256 + t, r = idx >> 5, c4 = idx & 31;
      int row = rt * 64 + c * 32 + r;
      size_t o = (size_t)row * 2048 + ct * 128 + c4 * 4;
      f32x4 p = pref[c][i];
      f32x4 s = *(const f32x4*)&u.stage[r * 132 + c4 * 4];
      float g = gate_s[c * 32 + r];
      f32x4 ov;
      #pragma unroll
      for (int j = 0; j < 4; j++) ov[j] = p[j] + g * s[j];
      *(f32x4*)(out + o) = ov;
    }
  }
}

// ============================ launch ============================
extern "C" void kernel_launch(void* const* d_in, const int* in_sizes, int n_in,
                              void* d_out, int out_size, void* d_ws, size_t ws_size,
                              hipStream_t stream) {
  const float* hs      = (const float*)d_in[0];
  const float* primary = (const float*)d_in[1];
  const float* qw      = (const float*)d_in[2];
  const float* sk      = (const float*)d_in[3];
  const float* sv      = (const float*)d_in[4];
  const float* rel     = (const float*)d_in[5];
  const float* vdw     = (const float*)d_in[6];
  const float* vup     = (const float*)d_in[7];
  unsigned char* ws = (unsigned char*)d_ws;
  float* out = (float*)d_out;

  k_prep<<<dim3(256), dim3(256), 0, stream>>>(qw, sk, sv, vdw, vup, rel, ws);
  k_pv<<<dim3(64), dim3(256), 0, stream>>>(ws);
  k_qscore<<<dim3(512), dim3(256), 0, stream>>>(hs, ws);
  k_out<<<dim3(2048), dim3(256), 0, stream>>>(primary, out, ws);
}

// Round 13
// 83.795 us; speedup vs baseline: 1.6360x; 1.6360x over previous
//
#include <hip/hip_runtime.h>
#include <stdint.h>

// ============================ problem dims ============================
// hidden_states [4,2048,2048] f32, rows R=8192, H=2048, BD=N=VBD=256, top-8
// out = primary + sigmoid(top1) * gelu_lowrank(softmax_top8 @ gathered vals)
// Key restructure: down-proj is linear -> precompute PV = slot_values @ Wd^T
// (256x256) and gather from PV instead of materializing aux[8192][2048].
// R12 lesson: k_query+k_score fusion (BM=16) is structurally worse than the
// 48MB qp round-trip; (256,6) on k_out re-spills.  This is the R9-best config
// + barrier-free k_pv.

typedef float f32x4 __attribute__((ext_vector_type(4)));
typedef unsigned short u16x8 __attribute__((ext_vector_type(8)));
typedef unsigned short u16x4 __attribute__((ext_vector_type(4)));
typedef __bf16 bf16x8 __attribute__((ext_vector_type(8)));

// ============================ ws layout (bytes) ============================
#define WS_QW    0u          // u16 [256*2048]  q_proj_w bf16
#define WS_SK    1048576u    // u16 [256*256]   slot_keys bf16
#define WS_SV    1179648u    // u16 [256*2048]  slot_values bf16
#define WS_VDW   2228224u    // u16 [256*2048]  value_down_w bf16
#define WS_VUP   3276800u    // u16 [2048*256]  value_up_w bf16
#define WS_REL   4325376u    // f32 [256]       log(reliability)
#define WS_PV    4326400u    // f32 [256*256]   slot_values @ Wd^T
#define WS_GATE  4588544u    // f32 [8192]      sigmoid(top1)
#define WS_QP    4621312u    // f32 [2][8192][256] query split-K partials
#define WS_D     21398528u   // u16 [8192*256]  gelu(down) bf16
// total ~24.4 MB

static __device__ __forceinline__ unsigned short f2bf(float f) {
  union { float f; unsigned int u; } v; v.f = f;
  unsigned int r = v.u + 0x7FFFu + ((v.u >> 16) & 1u);
  return (unsigned short)(r >> 16);
}
static __device__ __forceinline__ bf16x8 as_bf16(u16x8 v) {
  return __builtin_bit_cast(bf16x8, v);
}
static __device__ __forceinline__ float gelu_tanh(float x) {
  float u = 0.7978845608028654f * (x + 0.044715f * x * x * x);
  return 0.5f * x * (1.0f + tanhf(u));
}

// ============================ K0: convert weights ============================
__global__ void k_prep(const float* __restrict__ qw, const float* __restrict__ sk,
                       const float* __restrict__ sv, const float* __restrict__ vdw,
                       const float* __restrict__ vup, const float* __restrict__ rel,
                       unsigned char* __restrict__ ws) {
  unsigned short* o_qw  = (unsigned short*)(ws + WS_QW);
  unsigned short* o_sk  = (unsigned short*)(ws + WS_SK);
  unsigned short* o_sv  = (unsigned short*)(ws + WS_SV);
  unsigned short* o_vdw = (unsigned short*)(ws + WS_VDW);
  unsigned short* o_vup = (unsigned short*)(ws + WS_VUP);
  float* o_rel = (float*)(ws + WS_REL);
  int tid = blockIdx.x * blockDim.x + threadIdx.x;
  int stride = gridDim.x * blockDim.x;
  for (int g = tid; g < 540736; g += stride) {
    const float* src; unsigned short* dst; int i;
    if      (g < 131072) { src = qw;  dst = o_qw;  i = g; }
    else if (g < 147456) { src = sk;  dst = o_sk;  i = g - 131072; }
    else if (g < 278528) { src = sv;  dst = o_sv;  i = g - 147456; }
    else if (g < 409600) { src = vdw; dst = o_vdw; i = g - 278528; }
    else if (g < 540672) { src = vup; dst = o_vup; i = g - 409600; }
    else {
      int i4 = (g - 540672) * 4;
      #pragma unroll
      for (int j = 0; j < 4; j++) o_rel[i4 + j] = logf(fmaxf(rel[i4 + j], 1e-10f));
      continue;
    }
    f32x4 v = *(const f32x4*)(src + (size_t)i * 4);
    u16x4 o;
    #pragma unroll
    for (int j = 0; j < 4; j++) o[j] = f2bf(v[j]);
    *(u16x4*)(dst + (size_t)i * 4) = o;
  }
}

// ============================ K_PV: PV = sv @ vdw^T (barrier-free K) ============================
// 256 blocks = 16x16 output tiles.  4 waves split K=2048 (512 each); MFMA
// operands load DIRECTLY global->fragment (lane: row=l&15, k=(l>>4)*8 -> one
// contiguous u16x8) -- zero barriers in the K loop.  One LDS reduce at end.
__global__ __launch_bounds__(256, 4) void k_pv(unsigned char* __restrict__ ws) {
  const unsigned short* sv  = (const unsigned short*)(ws + WS_SV);
  const unsigned short* vdw = (const unsigned short*)(ws + WS_VDW);
  float* PV = (float*)(ws + WS_PV);
  __shared__ float red[4][16][16];
  int t = threadIdx.x, lane = t & 63, w = t >> 6;
  int nt = blockIdx.x >> 4, vt = blockIdx.x & 15;
  const unsigned short* aLane = sv  + (size_t)(nt * 16 + (lane & 15)) * 2048 + (lane >> 4) * 8 + w * 512;
  const unsigned short* bLane = vdw + (size_t)(vt * 16 + (lane & 15)) * 2048 + (lane >> 4) * 8 + w * 512;
  f32x4 acc = {0.f, 0.f, 0.f, 0.f};
  #pragma unroll
  for (int kt = 0; kt < 16; kt++) {
    bf16x8 a = as_bf16(*(const u16x8*)(aLane + kt * 32));
    bf16x8 b = as_bf16(*(const u16x8*)(bLane + kt * 32));
    acc = __builtin_amdgcn_mfma_f32_16x16x32_bf16(a, b, acc, 0, 0, 0);
  }
  int col = lane & 15, row0 = (lane >> 4) * 4;
  #pragma unroll
  for (int j = 0; j < 4; j++) red[w][row0 + j][col] = acc[j];
  __syncthreads();
  if (w == 0) {
    #pragma unroll
    for (int i = 0; i < 4; i++) {
      int idx = i * 64 + lane, r = idx >> 4, c = idx & 15;
      float s = red[0][r][c] + red[1][r][c] + red[2][r][c] + red[3][r][c];
      PV[(nt * 16 + r) * 256 + vt * 16 + c] = s;
    }
  }
}

// ============================ K1: query GEMM (split-K=2, pipelined) ============================
// qpart[ks][r][d] = hs[r, ks*1024 : +1024] @ qw^T.  BM=32, BN=256(all of BD).
// 512 blocks (256 row tiles x 2 k-slices) -> 4 blocks/CU.  Register-prefetch
// pipeline: issue tile t+1's global loads before the MFMA phase.
__global__ __launch_bounds__(256, 4) void k_query(const float* __restrict__ hs,
                                                  unsigned char* __restrict__ ws) {
  const unsigned short* qw = (const unsigned short*)(ws + WS_QW);
  float* qp = (float*)(ws + WS_QP);
  __shared__ __align__(16) unsigned short As[32 * 64];    // 4 KB
  __shared__ __align__(16) unsigned short Bs[256 * 64];   // 32 KB
  int t = threadIdx.x, lane = t & 63, w = t >> 6;
  int rt = blockIdx.x >> 1, ks = blockIdx.x & 1;
  int row0 = rt * 32, kbase = ks * 1024;
  f32x4 acc[2][4] = {};
  int sr = t >> 3, sc = t & 7;   // staging coords: 32 rows x 8 chunks of 8
  const float* aptr = hs + (size_t)(row0 + sr) * 2048 + kbase + sc * 8;
  const unsigned short* bptr = qw + (size_t)sr * 2048 + kbase + sc * 8;
  f32x4 pa0, pa1;
  u16x8 pb0, pb1, pb2, pb3, pb4, pb5, pb6, pb7;
  // prologue: tile 0 -> regs
  pa0 = *(const f32x4*)(aptr);
  pa1 = *(const f32x4*)(aptr + 4);
  pb0 = *(const u16x8*)(bptr + (size_t)0 * 32 * 2048);
  pb1 = *(const u16x8*)(bptr + (size_t)1 * 32 * 2048);
  pb2 = *(const u16x8*)(bptr + (size_t)2 * 32 * 2048);
  pb3 = *(const u16x8*)(bptr + (size_t)3 * 32 * 2048);
  pb4 = *(const u16x8*)(bptr + (size_t)4 * 32 * 2048);
  pb5 = *(const u16x8*)(bptr + (size_t)5 * 32 * 2048);
  pb6 = *(const u16x8*)(bptr + (size_t)6 * 32 * 2048);
  pb7 = *(const u16x8*)(bptr + (size_t)7 * 32 * 2048);
  for (int kt = 0; kt < 16; kt++) {
    __syncthreads();   // previous tile's LDS readers done
    {  // stage regs -> LDS (A: fp32->bf16)
      u16x8 o;
      #pragma unroll
      for (int j = 0; j < 4; j++) { o[j] = f2bf(pa0[j]); o[4 + j] = f2bf(pa1[j]); }
      *(u16x8*)&As[sr * 64 + ((sc ^ (sr & 7)) * 8)] = o;
      u16x8 pb[8] = {pb0, pb1, pb2, pb3, pb4, pb5, pb6, pb7};
      #pragma unroll
      for (int i = 0; i < 8; i++) {
        int n = i * 32 + sr;
        *(u16x8*)&Bs[n * 64 + ((sc ^ (n & 7)) * 8)] = pb[i];
      }
    }
    __syncthreads();
    if (kt < 15) {  // prefetch tile kt+1 into regs (overlaps MFMA below)
      int off = (kt + 1) * 64;
      pa0 = *(const f32x4*)(aptr + off);
      pa1 = *(const f32x4*)(aptr + off + 4);
      pb0 = *(const u16x8*)(bptr + (size_t)0 * 32 * 2048 + off);
      pb1 = *(const u16x8*)(bptr + (size_t)1 * 32 * 2048 + off);
      pb2 = *(const u16x8*)(bptr + (size_t)2 * 32 * 2048 + off);
      pb3 = *(const u16x8*)(bptr + (size_t)3 * 32 * 2048 + off);
      pb4 = *(const u16x8*)(bptr + (size_t)4 * 32 * 2048 + off);
      pb5 = *(const u16x8*)(bptr + (size_t)5 * 32 * 2048 + off);
      pb6 = *(const u16x8*)(bptr + (size_t)6 * 32 * 2048 + off);
      pb7 = *(const u16x8*)(bptr + (size_t)7 * 32 * 2048 + off);
    }
    #pragma unroll
    for (int kk = 0; kk < 2; kk++) {
      int ck = kk * 4 + (lane >> 4);
      bf16x8 a[2], b[4];
      #pragma unroll
      for (int mf = 0; mf < 2; mf++) {
        int arow = mf * 16 + (lane & 15);
        a[mf] = as_bf16(*(const u16x8*)&As[arow * 64 + ((ck ^ (arow & 7)) * 8)]);
      }
      #pragma unroll
      for (int nf = 0; nf < 4; nf++) {
        int brow = w * 64 + nf * 16 + (lane & 15);
        b[nf] = as_bf16(*(const u16x8*)&Bs[brow * 64 + ((ck ^ (brow & 7)) * 8)]);
      }
      #pragma unroll
      for (int mf = 0; mf < 2; mf++)
        #pragma unroll
        for (int nf = 0; nf < 4; nf++)
          acc[mf][nf] = __builtin_amdgcn_mfma_f32_16x16x32_bf16(a[mf], b[nf], acc[mf][nf], 0, 0, 0);
    }
  }
  float* outp = qp + (size_t)ks * 8192 * 256;
  #pragma unroll
  for (int mf = 0; mf < 2; mf++) {
    int row = row0 + mf * 16 + (lane >> 4) * 4;
    #pragma unroll
    for (int nf = 0; nf < 4; nf++) {
      int col = w * 64 + nf * 16 + (lane & 15);
      #pragma unroll
      for (int j = 0; j < 4; j++) outp[(size_t)(row + j) * 256 + col] = acc[mf][nf][j];
    }
  }
}

// ============================ K2: scores + wave-parallel top8 + PV gather ============================
#define QSTR 264   // ushort stride
#define SSTR 260   // f32 stride: 1040B row -> 16B aligned, contiguous reads
__global__ __launch_bounds__(256, 4) void k_score(unsigned char* __restrict__ ws) {
  const float* qp = (const float*)(ws + WS_QP);
  const unsigned short* sk = (const unsigned short*)(ws + WS_SK);
  const float* relm = (const float*)(ws + WS_REL);
  const float* PV = (const float*)(ws + WS_PV);
  float* gates = (float*)(ws + WS_GATE);
  unsigned short* D = (unsigned short*)(ws + WS_D);
  __shared__ __align__(16) unsigned short Qs[16 * QSTR];
  __shared__ __align__(16) float Ss[16 * SSTR];
  int t = threadIdx.x, lane = t & 63, w = t >> 6;
  int row0 = blockIdx.x * 16;
  // phase 1: query = qpart0 + qpart1 -> bf16 -> LDS (16 rows x 256 cols)
  #pragma unroll
  for (int i = 0; i < 4; i++) {
    int id = i * 256 + t, r = id >> 6, c4 = id & 63;
    const float* p0 = qp + (size_t)(row0 + r) * 256 + c4 * 4;
    f32x4 a = *(const f32x4*)p0;
    f32x4 b = *(const f32x4*)(p0 + 8192 * 256);
    u16x4 o;
    #pragma unroll
    for (int j = 0; j < 4; j++) o[j] = f2bf(a[j] + b[j]);
    *(u16x4*)&Qs[r * QSTR + c4 * 4] = o;
  }
  __syncthreads();
  // phase 2: scores[16][256] = Q @ sk^T / 16 + rel_mask
  {
    f32x4 acc[4] = {};
    for (int ksb = 0; ksb < 8; ksb++) {
      int ck = lane >> 4;
      bf16x8 a = as_bf16(*(const u16x8*)&Qs[(lane & 15) * QSTR + ksb * 32 + ck * 8]);
      #pragma unroll
      for (int nf = 0; nf < 4; nf++) {
        int n = w * 64 + nf * 16 + (lane & 15);
        bf16x8 b = as_bf16(*(const u16x8*)&sk[(size_t)n * 256 + ksb * 32 + ck * 8]);
        acc[nf] = __builtin_amdgcn_mfma_f32_16x16x32_bf16(a, b, acc[nf], 0, 0, 0);
      }
    }
    #pragma unroll
    for (int nf = 0; nf < 4; nf++) {
      int n = w * 64 + nf * 16 + (lane & 15);
      float rm = relm[n];
      int rr = (lane >> 4) * 4;
      #pragma unroll
      for (int j = 0; j < 4; j++) Ss[(rr + j) * SSTR + n] = acc[nf][j] * 0.0625f + rm;
    }
  }
  __syncthreads();
  // phase 3: wave w handles rows w*4 .. w*4+3
  for (int rr = 0; rr < 4; rr++) {
    int row = w * 4 + rr;
    f32x4 sv4 = *(const f32x4*)&Ss[row * SSTR + lane * 4];
    unsigned int key[4];
    #pragma unroll
    for (int j = 0; j < 4; j++) {
      unsigned int u = __builtin_bit_cast(unsigned int, sv4[j]);
      unsigned int os = (u & 0x80000000u) ? ~u : (u | 0x80000000u);
      key[j] = (os & 0xFFFFFF00u) | (unsigned int)(255 - (lane * 4 + j));
    }
    unsigned int win[8];
    #pragma unroll
    for (int e = 0; e < 8; e++) {
      unsigned int m01 = key[0] > key[1] ? key[0] : key[1];
      unsigned int m23 = key[2] > key[3] ? key[2] : key[3];
      unsigned int m = m01 > m23 ? m01 : m23;
      #pragma unroll
      for (int d = 1; d < 64; d <<= 1) {
        unsigned int o = (unsigned int)__shfl_xor((int)m, d, 64);
        m = o > m ? o : m;
      }
      win[e] = m;
      #pragma unroll
      for (int j = 0; j < 4; j++) if (key[j] == m) key[j] = 0u;
    }
    // decode (all lanes redundantly)
    float s8[8]; int i8[8];
    #pragma unroll
    for (int e = 0; e < 8; e++) {
      i8[e] = 255 - (int)(win[e] & 0xFFu);
      unsigned int os = win[e] & 0xFFFFFF00u;
      unsigned int u = (os & 0x80000000u) ? (os ^ 0x80000000u) : ~os;
      s8[e] = __builtin_bit_cast(float, u);
    }
    float m0 = s8[0], sum = 0.f, we[8];
    #pragma unroll
    for (int e = 0; e < 8; e++) { we[e] = expf(s8[e] - m0); sum += we[e]; }
    float inv = 1.f / sum;
    // PV gather: lane l owns cols 4l..4l+3 (f32x4, contiguous 1KB per slot)
    f32x4 accv = {0.f, 0.f, 0.f, 0.f};
    #pragma unroll
    for (int e = 0; e < 8; e++) {
      float wk = we[e] * inv;
      f32x4 p = *(const f32x4*)(PV + (size_t)i8[e] * 256 + lane * 4);
      #pragma unroll
      for (int j = 0; j < 4; j++) accv[j] += wk * p[j];
    }
    u16x4 o;
    #pragma unroll
    for (int j = 0; j < 4; j++) o[j] = f2bf(gelu_tanh(accv[j]));
    *(u16x4*)&D[(size_t)(row0 + row) * 256 + lane * 4] = o;
    if (lane == 0) gates[row0 + row] = 1.f / (1.f + expf(-m0));
  }
}

// ============================ K3: up-GEMM + epilogue (R9 best: 46.2us) ============================
// out[r,h] = primary[r,h] + gate[r] * (D[r,:] @ vup[h,:])   K=256
// BM=64 x BN=128, 2048 blocks (128 row x 16 col, XCD swizzle), (256,4).
// K-loop reg-prefetch pipeline + primary pref[2][4] double buffer.
// Tripwires: VGPR_Count ~64, WRITE_SIZE == 65536 KB (else spilling).
union KOutLds {
  unsigned short AB[12288];        // As = AB[0..4095] (64x64), Bs = AB+4096 (128x64)
  float stage[32 * 132];           // epilogue restage
};
__global__ __launch_bounds__(256, 4) void k_out(const float* __restrict__ primary,
                                                float* __restrict__ out,
                                                unsigned char* __restrict__ ws) {
  const unsigned short* D = (const unsigned short*)(ws + WS_D);
  const unsigned short* vup = (const unsigned short*)(ws + WS_VUP);
  const float* gates = (const float*)(ws + WS_GATE);
  __shared__ __align__(16) KOutLds u;
  __shared__ float gate_s[64];
  unsigned short* As = u.AB;
  unsigned short* Bs = u.AB + 4096;
  int t = threadIdx.x, lane = t & 63, w = t >> 6;
  int bid = blockIdx.x;
  int L = (bid & 7) * 256 + (bid >> 3);   // bijective: 2048 % 8 == 0
  int rt = L >> 4, ct = L & 15;
  int wm = w >> 1, wn = w & 1;
  const float* pbase = primary + (size_t)(rt * 64 + (t >> 5)) * 2048 + ct * 128 + (t & 31) * 4;
  f32x4 pref[2][4];
  #pragma unroll
  for (int i = 0; i < 4; i++)
    pref[0][i] = *(const f32x4*)(pbase + (size_t)(i * 8) * 2048);
  int sr = t >> 3, sc = t & 7;
  const unsigned short* aptr = D + (size_t)(rt * 64 + sr) * 256 + sc * 8;
  const unsigned short* bptr = vup + (size_t)(ct * 128 + sr) * 256 + sc * 8;
  u16x8 pA0, pA1, pB0, pB1, pB2, pB3;
  pA0 = *(const u16x8*)(aptr);
  pA1 = *(const u16x8*)(aptr + 32 * 256);
  pB0 = *(const u16x8*)(bptr);
  pB1 = *(const u16x8*)(bptr + 32 * 256);
  pB2 = *(const u16x8*)(bptr + 64 * 256);
  pB3 = *(const u16x8*)(bptr + 96 * 256);
  if (t < 64) gate_s[t] = gates[rt * 64 + t];
  f32x4 acc[2][4] = {};
  for (int k0 = 0; k0 < 256; k0 += 64) {
    __syncthreads();
    {
      int r0 = sr, r1 = sr + 32, r2 = sr + 64, r3 = sr + 96;
      *(u16x8*)&As[r0 * 64 + ((sc ^ (r0 & 7)) * 8)] = pA0;
      *(u16x8*)&As[r1 * 64 + ((sc ^ (r1 & 7)) * 8)] = pA1;
      *(u16x8*)&Bs[r0 * 64 + ((sc ^ (r0 & 7)) * 8)] = pB0;
      *(u16x8*)&Bs[r1 * 64 + ((sc ^ (r1 & 7)) * 8)] = pB1;
      *(u16x8*)&Bs[r2 * 64 + ((sc ^ (r2 & 7)) * 8)] = pB2;
      *(u16x8*)&Bs[r3 * 64 + ((sc ^ (r3 & 7)) * 8)] = pB3;
    }
    __syncthreads();
    if (k0 < 192) {
      int off = k0 + 64;
      pA0 = *(const u16x8*)(aptr + off);
      pA1 = *(const u16x8*)(aptr + 32 * 256 + off);
      pB0 = *(const u16x8*)(bptr + off);
      pB1 = *(const u16x8*)(bptr + 32 * 256 + off);
      pB2 = *(const u16x8*)(bptr + 64 * 256 + off);
      pB3 = *(const u16x8*)(bptr + 96 * 256 + off);
    }
    #pragma unroll
    for (int kk = 0; kk < 2; kk++) {
      int ck = kk * 4 + (lane >> 4);
      bf16x8 a[2], b[4];
      #pragma unroll
      for (int mf = 0; mf < 2; mf++) {
        int ar = wm * 32 + mf * 16 + (lane & 15);
        a[mf] = as_bf16(*(const u16x8*)&As[ar * 64 + ((ck ^ (ar & 7)) * 8)]);
      }
      #pragma unroll
      for (int nf = 0; nf < 4; nf++) {
        int br = wn * 64 + nf * 16 + (lane & 15);
        b[nf] = as_bf16(*(const u16x8*)&Bs[br * 64 + ((ck ^ (br & 7)) * 8)]);
      }
      #pragma unroll
      for (int mf = 0; mf < 2; mf++)
        #pragma unroll
        for (int nf = 0; nf < 4; nf++)
          acc[mf][nf] = __builtin_amdgcn_mfma_f32_16x16x32_bf16(a[mf], b[nf], acc[mf][nf], 0, 0, 0);
    }
  }
  #pragma unroll
  for (int c = 0; c < 2; c++) {
    __syncthreads();
    if (wm == c) {
      #pragma unroll
      for (int mf = 0; mf < 2; mf++) {
        #pragma unroll
        for (int nf = 0; nf < 4; nf++) {
          int col = wn * 64 + nf * 16 + (lane & 15);
          #pragma unroll
          for (int j = 0; j < 4; j++) {
            int r = mf * 16 + (lane >> 4) * 4 + j;
            u.stage[r * 132 + col] = acc[mf][nf][j];
          }
        }
      }
    }
    if (c == 0) {
      #pragma unroll
      for (int i = 0; i < 4; i++)
        pref[1][i] = *(const f32x4*)(pbase + (size_t)(32 + i * 8) * 2048);
    }
    __syncthreads();
    #pragma unroll
    for (int i = 0; i < 4; i++) {
      int idx = i * 256 + t, r = idx >> 5, c4 = idx & 31;
      int row = rt * 64 + c * 32 + r;
      size_t o = (size_t)row * 2048 + ct * 128 + c4 * 4;
      f32x4 p = pref[c][i];
      f32x4 s = *(const f32x4*)&u.stage[r * 132 + c4 * 4];
      float g = gate_s[c * 32 + r];
      f32x4 ov;
      #pragma unroll
      for (int j = 0; j < 4; j++) ov[j] = p[j] + g * s[j];
      *(f32x4*)(out + o) = ov;
    }
  }
}

// ============================ launch ============================
extern "C" void kernel_launch(void* const* d_in, const int* in_sizes, int n_in,
                              void* d_out, int out_size, void* d_ws, size_t ws_size,
                              hipStream_t stream) {
  const float* hs      = (const float*)d_in[0];
  const float* primary = (const float*)d_in[1];
  const float* qw      = (const float*)d_in[2];
  const float* sk      = (const float*)d_in[3];
  const float* sv      = (const float*)d_in[4];
  const float* rel     = (const float*)d_in[5];
  const float* vdw     = (const float*)d_in[6];
  const float* vup     = (const float*)d_in[7];
  unsigned char* ws = (unsigned char*)d_ws;
  float* out = (float*)d_out;

  k_prep<<<dim3(256), dim3(256), 0, stream>>>(qw, sk, sv, vdw, vup, rel, ws);
  k_pv<<<dim3(256), dim3(256), 0, stream>>>(ws);
  k_query<<<dim3(512), dim3(256), 0, stream>>>(hs, ws);
  k_score<<<dim3(512), dim3(256), 0, stream>>>(ws);
  k_out<<<dim3(2048), dim3(256), 0, stream>>>(primary, out, ws);
}